// Round 14
// baseline (1399.907 us; speedup 1.0000x reference)
//
#include <hip/hip_runtime.h>
#include <hip/hip_bf16.h>

#define EPSBN 2e-5f

typedef __attribute__((ext_vector_type(8))) short short8v;
typedef __attribute__((ext_vector_type(4))) float f32x4;

__device__ inline unsigned short f2bf(float f) {
  unsigned u = __float_as_uint(f);
  unsigned r = (u + 0x7FFFu + ((u >> 16) & 1u)) >> 16;
  return (unsigned short)r;
}
__device__ inline float bf2f(unsigned short h) {
  return __uint_as_float(((unsigned)h) << 16);
}

// ---------------------------------------------------------------------------
// Padded x staging
// ---------------------------------------------------------------------------
constexpr int XPADL = 9984;
constexpr int XPADR = 14336;
constexpr int PROW = XPADL + 32768 + XPADR;  // 57088

__global__ __launch_bounds__(256) void pad_x_kernel(const float* __restrict__ x,
                                                    float* __restrict__ xp) {
  int i = blockIdx.x * 256 + threadIdx.x;
  if (i >= 8 * PROW) return;
  int b = i / PROW;
  int pos = i - b * PROW - XPADL;
  xp[i] = (pos >= 0 && pos < 32768) ? x[b * 32768 + pos] : 0.f;
}

// ---------------------------------------------------------------------------
// Pack w1 [51][79] -> per-s split bf16 (1/2^s folded), [s][hi/lo][64][96]
// ---------------------------------------------------------------------------
__global__ __launch_bounds__(256) void pack_w1_kernel(
    const float* __restrict__ W, short* __restrict__ A) {
  int idx = blockIdx.x * 256 + threadIdx.x;
  if (idx >= 9 * 64 * 96) return;
  int s = idx / (64 * 96);
  int rem = idx - s * 64 * 96;
  int co = rem / 96;
  int k = rem - co * 96;
  float v = 0.f;
  if (co < 51 && k < 79)
    v = W[co * 79 + k] * __uint_as_float((unsigned)(127 - s) << 23);
  unsigned short hi = f2bf(v);
  unsigned short lo = f2bf(v - bf2f(hi));
  A[(size_t)s * 2 * 64 * 96 + co * 96 + k] = (short)hi;
  A[(size_t)s * 2 * 64 * 96 + 64 * 96 + co * 96 + k] = (short)lo;
}

// ---------------------------------------------------------------------------
// lift_mfma: lift conv K=79 as bf16 MFMA GEMM + fused pool4 (R12, unchanged)
// ---------------------------------------------------------------------------
__global__ __launch_bounds__(256) void lift_mfma_kernel(
    const float* __restrict__ xp, const short* __restrict__ Apk1,
    float* __restrict__ y1) {
  constexpr int P = 104;
  const int lc = blockIdx.x;
  const int s = blockIdx.y;
  const int b = blockIdx.z;
  const int d = 1 << s;
  const int l0 = lc * 64;
  const int tid = threadIdx.x;
  const int lane = tid & 63;
  const int quad = lane >> 4;
  const int n0 = lane & 15;
  const int wv = tid >> 6;
  const int coBase = wv * 16;

  __shared__ __align__(16) short Bh[64 * P];
  __shared__ __align__(16) short Bl[64 * P];

  const float* xrow = xp + b * PROW + XPADL;

  const int nB = tid & 63;
  const int og = tid >> 6;
#pragma unroll
  for (int r = 0; r < 3; ++r) {
    const int oct = og + 4 * r;
    const int kb = oct * 8;
    float v[8];
#pragma unroll
    for (int j = 0; j < 8; ++j) v[j] = xrow[l0 + nB + (kb + j - 39) * d];
    unsigned h[8], lo[8];
#pragma unroll
    for (int j = 0; j < 8; ++j) {
      unsigned u = __float_as_uint(v[j]);
      h[j] = u >> 16;
      float lof = v[j] - __uint_as_float(u & 0xffff0000u);
      lo[j] = __float_as_uint(lof) >> 16;
    }
    uint4 ph, pl;
    ph.x = h[0] | (h[1] << 16);
    ph.y = h[2] | (h[3] << 16);
    ph.z = h[4] | (h[5] << 16);
    ph.w = h[6] | (h[7] << 16);
    pl.x = lo[0] | (lo[1] << 16);
    pl.y = lo[2] | (lo[3] << 16);
    pl.z = lo[4] | (lo[5] << 16);
    pl.w = lo[6] | (lo[7] << 16);
    *(uint4*)(Bh + nB * P + kb) = ph;
    *(uint4*)(Bl + nB * P + kb) = pl;
  }

  const short* ApkS = Apk1 + (size_t)s * 2 * 64 * 96;
  const short* arowH = ApkS + (coBase + n0) * 96;
  const short* arowL = arowH + 64 * 96;

  __syncthreads();

  f32x4 acc[4];
#pragma unroll
  for (int t = 0; t < 4; ++t) acc[t] = (f32x4){0.f, 0.f, 0.f, 0.f};

#pragma unroll
  for (int ks = 0; ks < 3; ++ks) {
    short8v ah = *(const short8v*)(arowH + ks * 32 + quad * 8);
    short8v al = *(const short8v*)(arowL + ks * 32 + quad * 8);
#pragma unroll
    for (int t = 0; t < 4; ++t) {
      const int n = n0 + 16 * t;
      short8v bh = *(const short8v*)(Bh + n * P + ks * 32 + quad * 8);
      short8v bl = *(const short8v*)(Bl + n * P + ks * 32 + quad * 8);
      acc[t] = __builtin_amdgcn_mfma_f32_16x16x32_bf16(ah, bh, acc[t], 0, 0, 0);
      acc[t] = __builtin_amdgcn_mfma_f32_16x16x32_bf16(ah, bl, acc[t], 0, 0, 0);
      acc[t] = __builtin_amdgcn_mfma_f32_16x16x32_bf16(al, bh, acc[t], 0, 0, 0);
    }
  }

#pragma unroll
  for (int reg = 0; reg < 4; ++reg) {
    const int co = coBase + quad * 4 + reg;
#pragma unroll
    for (int t = 0; t < 4; ++t) {
      float u = acc[t][reg];
      u = fmaxf(u, __shfl_xor(u, 1));
      u = fmaxf(u, __shfl_xor(u, 2));
      if ((n0 & 3) == 0 && co < 51) {
        const int l1 = (l0 >> 2) + t * 4 + (n0 >> 2);
        y1[(((size_t)b * 51 + co) * 9 + s) * 8192 + l1] = u;
      }
    }
  }
}

// ---------------------------------------------------------------------------
// Per-channel sum/sumsq over [B,C,HL], HL split NS ways; grid (C,B,NS)
// ---------------------------------------------------------------------------
__global__ __launch_bounds__(256) void stats_kernel(
    const float* __restrict__ Y, float* __restrict__ st, int C, int HL,
    int NS) {
  const int c = blockIdx.x, b = blockIdx.y, z = blockIdx.z;
  const int slice = HL / NS;
  const float* p = Y + ((size_t)b * C + c) * HL + (size_t)z * slice;
  float s = 0.f, q = 0.f;
  for (int i = threadIdx.x; i < slice; i += 256) {
    float v = p[i];
    s += v;
    q += v * v;
  }
#pragma unroll
  for (int off = 32; off > 0; off >>= 1) {
    s += __shfl_down(s, off, 64);
    q += __shfl_down(q, off, 64);
  }
  __shared__ float ls[4], lq[4];
  const int wid = threadIdx.x >> 6, lane = threadIdx.x & 63;
  if (lane == 0) { ls[wid] = s; lq[wid] = q; }
  __syncthreads();
  if (threadIdx.x == 0) {
    atomicAdd(&st[c], ls[0] + ls[1] + ls[2] + ls[3]);
    atomicAdd(&st[512 + c], lq[0] + lq[1] + lq[2] + lq[3]);
  }
}

// ---------------------------------------------------------------------------
// BN(train)+ReLU+pool4, fp32 out
// ---------------------------------------------------------------------------
__global__ __launch_bounds__(256) void bnrelu_pool_kernel(
    const float* __restrict__ Y, const float* __restrict__ st,
    const float* __restrict__ g, const float* __restrict__ bb,
    float* __restrict__ Z, int C, int H, int Lin, float invN,
    unsigned int total) {
  unsigned int idx = blockIdx.x * 256u + threadIdx.x;
  if (idx >= total) return;
  const unsigned int Lo = (unsigned int)(Lin >> 2);
  unsigned int lo = idx % Lo;
  unsigned int r1 = idx / Lo;
  unsigned int h = r1 % (unsigned int)H;
  unsigned int r2 = r1 / (unsigned int)H;
  unsigned int c = r2 % (unsigned int)C;
  unsigned int b = r2 / (unsigned int)C;
  float m = st[c] * invN;
  float v = st[512 + c] * invN - m * m;
  float sc = g[c] * rsqrtf(v + EPSBN);
  float bi = bb[c] - m * sc;
  const float* p = Y + (((size_t)b * C + c) * H + h) * Lin + 4u * lo;
  float a0 = p[0] * sc + bi, a1 = p[1] * sc + bi;
  float a2 = p[2] * sc + bi, a3 = p[3] * sc + bi;
  float r = fmaxf(fmaxf(a0, a1), fmaxf(a2, a3));
  Z[idx] = fmaxf(r, 0.f);
}

// ---- same, bf16 out
__global__ __launch_bounds__(256) void bnrelu_pool_bf16_kernel(
    const float* __restrict__ Y, const float* __restrict__ st,
    const float* __restrict__ g, const float* __restrict__ bb,
    unsigned short* __restrict__ Z, int C, int H, int Lin, float invN,
    unsigned int total) {
  unsigned int idx = blockIdx.x * 256u + threadIdx.x;
  if (idx >= total) return;
  const unsigned int Lo = (unsigned int)(Lin >> 2);
  unsigned int lo = idx % Lo;
  unsigned int r1 = idx / Lo;
  unsigned int h = r1 % (unsigned int)H;
  unsigned int r2 = r1 / (unsigned int)H;
  unsigned int c = r2 % (unsigned int)C;
  unsigned int b = r2 / (unsigned int)C;
  float m = st[c] * invN;
  float v = st[512 + c] * invN - m * m;
  float sc = g[c] * rsqrtf(v + EPSBN);
  float bi = bb[c] - m * sc;
  const float* p = Y + (((size_t)b * C + c) * H + h) * Lin + 4u * lo;
  float a0 = p[0] * sc + bi, a1 = p[1] * sc + bi;
  float a2 = p[2] * sc + bi, a3 = p[3] * sc + bi;
  float r = fmaxf(fmaxf(a0, a1), fmaxf(a2, a3));
  Z[idx] = f2bf(fmaxf(r, 0.f));
}

// ---------------------------------------------------------------------------
// BN(train)+ReLU elementwise, fp32 / bf16 out
// ---------------------------------------------------------------------------
__global__ __launch_bounds__(256) void bnrelu_kernel(
    const float* __restrict__ Y, const float* __restrict__ st,
    const float* __restrict__ g, const float* __restrict__ bb,
    float* __restrict__ A, int C, int HL, float invN, unsigned int total) {
  unsigned int idx = blockIdx.x * 256u + threadIdx.x;
  if (idx >= total) return;
  unsigned int c = (idx / (unsigned int)HL) % (unsigned int)C;
  float m = st[c] * invN;
  float v = st[512 + c] * invN - m * m;
  float sc = g[c] * rsqrtf(v + EPSBN);
  float bi = bb[c] - m * sc;
  A[idx] = fmaxf(fmaf(Y[idx], sc, bi), 0.f);
}

__global__ __launch_bounds__(256) void bnrelu_bf16_kernel(
    const float* __restrict__ Y, const float* __restrict__ st,
    const float* __restrict__ g, const float* __restrict__ bb,
    unsigned short* __restrict__ A, int C, int HL, float invN,
    unsigned int total) {
  unsigned int idx = blockIdx.x * 256u + threadIdx.x;
  if (idx >= total) return;
  unsigned int c = (idx / (unsigned int)HL) % (unsigned int)C;
  float m = st[c] * invN;
  float v = st[512 + c] * invN - m * m;
  float sc = g[c] * rsqrtf(v + EPSBN);
  float bi = bb[c] - m * sc;
  A[idx] = f2bf(fmaxf(fmaf(Y[idx], sc, bi), 0.f));
}

// ---------------------------------------------------------------------------
// Pack fp32 weights -> per-s split bf16 packs with 2^-(s+i) folded.
// ---------------------------------------------------------------------------
__global__ __launch_bounds__(256) void pack_w2_kernel(
    const float* __restrict__ W, short* __restrict__ A, int Co, int KTOT,
    int KPAD, int COPAD, int NS, int nk3) {
  int idx = blockIdx.x * 256 + threadIdx.x;
  const int CK = COPAD * KPAD;
  if (idx >= NS * CK) return;
  int s = idx / CK;
  int rem = idx - s * CK;
  int co = rem / KPAD;
  int kk = rem - co * KPAD;
  float v = 0.f;
  if (co < Co && kk < KTOT) {
    int i = (kk % nk3) / 3;
    float scale = __uint_as_float((unsigned)(127 - (s + i)) << 23);
    v = W[co * KTOT + kk] * scale;
  }
  unsigned short hi = f2bf(v);
  unsigned short lo = f2bf(v - bf2f(hi));
  A[(size_t)s * 2 * CK + co * KPAD + kk] = (short)hi;
  A[(size_t)s * 2 * CK + CK + co * KPAD + kk] = (short)lo;
}

// ---------------------------------------------------------------------------
// gg_mfma6: big-chunk (256 kk) bf16-MFMA GConvGG.
// Key change vs R13: K-chunks of 256 (was 64) -> gg2 has 2 barrier-pairs
// (was 8), gg3 has 1. Compiler drains vmcnt at every barrier (m97), so the
// win comes from fewer drains and 64-MFMA runs per barrier interval where
// fine-grained vmcnt scheduling works. No prefetch ring (defeated by drains).
// LDS pitch 264 shorts (132 words, gcd 4 -> uniform 8-deep banks).
// KPAD must be a multiple of 256 (Apack zero-padded; tables sized 512).
// ---------------------------------------------------------------------------
template <int NKv, int LT>
__global__ __launch_bounds__(256) void gg_mfma6_kernel(
    const unsigned short* __restrict__ X, const short* __restrict__ Apk,
    float* __restrict__ Y, float* __restrict__ stOut, int Ci, int Co, int Hin,
    int L, int nL, int KTOT, int KPAD, int COPAD) {
  constexpr int T = LT / 16;     // l-tiles per wave
  constexpr int KO = 256 / LT;   // octs per staging pass
  constexpr int RIT = 32 / KO;   // staging passes per 256-kk chunk
  constexpr int P2 = 264;        // LDS pitch (shorts)

  const int bx = blockIdx.x;
  const int lc = bx % nL;
  const int cog = bx / nL;
  const int s = blockIdx.y;
  const int b = blockIdx.z;
  const int Hout = Hin - NKv + 1;
  const int l0 = lc * LT;
  const int tid = threadIdx.x;
  const int lane = tid & 63;
  const int quad = lane >> 4;
  const int m0 = lane & 15;
  const int wv = tid >> 6;
  const int coBase = cog * 64 + wv * 16;

  __shared__ __align__(16) short Bh[LT * P2];
  __shared__ int roT[512];
  __shared__ int shT[512];

  for (int kk = tid; kk < 512; kk += 256) {
    int ro = 0, sh = -(1 << 30);
    if (kk < KTOT) {
      int ci = kk / (3 * NKv);
      int rem = kk - ci * (3 * NKv);
      int i = rem / 3;
      int k = rem - 3 * i;
      ro = (ci * Hin + s + i) * L;
      sh = (k - 1) * (1 << (s + i));
    }
    roT[kk] = ro;
    shT[kk] = sh;
  }
  __syncthreads();

  f32x4 acc[T];
#pragma unroll
  for (int t = 0; t < T; ++t) acc[t] = (f32x4){0.f, 0.f, 0.f, 0.f};

  const short* ApkS = Apk + (size_t)s * 2 * COPAD * KPAD;
  const short* arowH = ApkS + (size_t)(coBase + m0) * KPAD;
  const short* arowL = arowH + (size_t)COPAD * KPAD;
  const unsigned short* Xb = X + (size_t)b * Ci * Hin * L;

  const int lB = tid & (LT - 1);
  const int oc0 = tid / LT;  // 0..KO-1
  const int nch = KPAD >> 8;

  for (int c0 = 0; c0 < nch; ++c0) {
    // ---- gather 256 kk x LT l: RIT passes, all loads in flight together
    uint4 pk[RIT];
#pragma unroll
    for (int r = 0; r < RIT; ++r) {
      const int oct = oc0 + KO * r;
      const int kkb = (c0 << 8) + oct * 8;
      unsigned w[8];
#pragma unroll
      for (int j = 0; j < 8; ++j) {
        const int kk = kkb + j;
        const int pos = l0 + lB + shT[kk];
        const int posc = min(max(pos, 0), L - 1);
        unsigned u = (unsigned)Xb[roT[kk] + posc];
        w[j] = ((unsigned)pos < (unsigned)L) ? u : 0u;
      }
      pk[r].x = w[0] | (w[1] << 16);
      pk[r].y = w[2] | (w[3] << 16);
      pk[r].z = w[4] | (w[5] << 16);
      pk[r].w = w[6] | (w[7] << 16);
    }
#pragma unroll
    for (int r = 0; r < RIT; ++r)
      *(uint4*)(Bh + lB * P2 + (oc0 + KO * r) * 8) = pk[r];
    __syncthreads();
    // ---- 8 K-steps of 32 between barriers: long MFMA run, A loads
    // scheduled with fine-grained vmcnt by the compiler (no barrier inside)
#pragma unroll
    for (int ks = 0; ks < 8; ++ks) {
      const int aoff = (c0 << 8) + ks * 32 + quad * 8;
      short8v ah = *(const short8v*)(arowH + aoff);
      short8v al = *(const short8v*)(arowL + aoff);
#pragma unroll
      for (int t = 0; t < T; ++t) {
        const int l = m0 + 16 * t;
        short8v bf = *(const short8v*)(Bh + l * P2 + ks * 32 + quad * 8);
        acc[t] = __builtin_amdgcn_mfma_f32_16x16x32_bf16(ah, bf, acc[t], 0, 0, 0);
        acc[t] = __builtin_amdgcn_mfma_f32_16x16x32_bf16(al, bf, acc[t], 0, 0, 0);
      }
    }
    if (c0 + 1 < nch) __syncthreads();
  }

  // ---- epilogue: store + fused stats
#pragma unroll
  for (int reg = 0; reg < 4; ++reg) {
    const int co = coBase + quad * 4 + reg;
    if (co < Co) {
      float* yp = Y + (((size_t)b * Co + co) * Hout + s) * L + l0;
#pragma unroll
      for (int t = 0; t < T; ++t) yp[m0 + 16 * t] = acc[t][reg];
    }
  }
  if (stOut) {
#pragma unroll
    for (int reg = 0; reg < 4; ++reg) {
      float s1 = 0.f, s2 = 0.f;
#pragma unroll
      for (int t = 0; t < T; ++t) {
        s1 += acc[t][reg];
        s2 += acc[t][reg] * acc[t][reg];
      }
#pragma unroll
      for (int off = 1; off < 16; off <<= 1) {
        s1 += __shfl_xor(s1, off);
        s2 += __shfl_xor(s2, off);
      }
      const int co = coBase + quad * 4 + reg;
      if (m0 == 0 && co < Co) {
        atomicAdd(&stOut[co], s1);
        atomicAdd(&stOut[512 + co], s2);
      }
    }
  }
}

// ---------------------------------------------------------------------------
// gg_tail2: K-split no-LDS GConvGG (input pre-activated fp32).
// ---------------------------------------------------------------------------
template <int NK, int L, int COSUB>
__global__ __launch_bounds__(256) void gg_tail2_kernel(
    const float* __restrict__ X, const float* __restrict__ W,
    float* __restrict__ Y, int Ci, int Co, int Hin, int NSPLIT, int ciPer) {
  const int l = threadIdx.x % L;
  const int cs = threadIdx.x / L;
  const int co = blockIdx.x * COSUB + cs;
  const int s = blockIdx.y / NSPLIT;
  const int seg = blockIdx.y % NSPLIT;
  const int b = blockIdx.z;
  const int Hout = Hin - NK + 1;
  const int ciBeg = seg * ciPer;
  const int ciEnd = min(Ci, ciBeg + ciPer);

  float acc[NK];
#pragma unroll
  for (int i = 0; i < NK; ++i) acc[i] = 0.f;

  const float* wbase = W + (size_t)co * Ci * NK * 3;
  const float* xbase = X + ((size_t)b * Ci * Hin + s) * L;

  for (int ci = ciBeg; ci < ciEnd; ++ci) {
    const float* wp = wbase + ci * (NK * 3);
    const float* xr = xbase + ci * (Hin * L);
#pragma unroll
    for (int i = 0; i < NK; ++i) {
      const int d = 1 << (s + i);
      const float* row = xr + i * L;
      float xm = (l >= d) ? row[l - d] : 0.f;
      float xc = row[l];
      float xp = (l + d < L) ? row[l + d] : 0.f;
      acc[i] = fmaf(wp[3 * i], xm,
                    fmaf(wp[3 * i + 1], xc, fmaf(wp[3 * i + 2], xp, acc[i])));
    }
  }
  float out = 0.f;
#pragma unroll
  for (int i = 0; i < NK; ++i) {
    float invd = __uint_as_float((unsigned)(127 - (s + i)) << 23);
    out = fmaf(acc[i], invd, out);
  }
  atomicAdd(&Y[(((size_t)b * Co + co) * Hout + s) * L + l], out);
}

// ---------------------------------------------------------------------------
// Final: bn10+relu, mean over L, classifier
// ---------------------------------------------------------------------------
__global__ __launch_bounds__(256) void final_kernel(
    const float* __restrict__ Y, const float* __restrict__ st,
    const float* __restrict__ g, const float* __restrict__ bb,
    const float* __restrict__ w11, float* __restrict__ out) {
  const int b = blockIdx.x;
  const int tid = threadIdx.x;
  __shared__ float tch[408];
  for (int c = tid; c < 408; c += 256) {
    float m = st[c] * (1.f / 256.f);
    float v = st[512 + c] * (1.f / 256.f) - m * m;
    float sc = g[c] * rsqrtf(v + EPSBN);
    float bi = bb[c] - m * sc;
    const float* p = Y + ((size_t)b * 408 + c) * 32;
    float ssum = 0.f;
#pragma unroll
    for (int l = 0; l < 32; ++l) ssum += fmaxf(p[l] * sc + bi, 0.f);
    tch[c] = ssum * (1.f / 32.f);
  }
  __syncthreads();
  if (tid < 10) {
    float ssum = 0.f;
    for (int c = 0; c < 408; ++c) ssum += w11[tid * 408 + c] * tch[c];
    out[b * 10 + tid] = ssum;
  }
}

// ---------------------------------------------------------------------------
extern "C" void kernel_launch(void* const* d_in, const int* in_sizes, int n_in,
                              void* d_out, int out_size, void* d_ws,
                              size_t ws_size, hipStream_t stream) {
  const float* x = (const float*)d_in[0];
  const float* w1 = (const float*)d_in[1];
  const float* w2 = (const float*)d_in[2];
  const float* w3 = (const float*)d_in[3];
  const float* w4 = (const float*)d_in[4];
  const float* w5 = (const float*)d_in[5];
  const float* w6 = (const float*)d_in[6];
  const float* w7 = (const float*)d_in[7];
  const float* w8 = (const float*)d_in[8];
  const float* w9 = (const float*)d_in[9];
  const float* w10 = (const float*)d_in[10];
  const float* w11 = (const float*)d_in[11];
  const float* gg[11];
  const float* bbv[11];
  for (int i = 1; i <= 10; ++i) {
    gg[i] = (const float*)d_in[12 + 2 * (i - 1)];
    bbv[i] = (const float*)d_in[12 + 2 * (i - 1) + 1];
  }

  float* ws = (float*)d_ws;
  const size_t AR0 = 0;
  const size_t AR1 = 30081024;
  const size_t STATS = 37601280;
  float* y1 = ws + AR0;
  float* xpad = ws + AR1;
  short* apk1 = (short*)(ws + AR1 + 460800);
  unsigned short* z1b = (unsigned short*)(ws + AR1);
  unsigned short* a3b = (unsigned short*)(ws + AR1);
  unsigned short* z3b = (unsigned short*)(ws + AR1);
  unsigned short* a5b = (unsigned short*)(ws + AR1 + 1500000);
  float* z5 = ws + AR1;
  float* a6 = ws + AR1 + 522240;
  float* a7 = ws + AR1 + 1148928;
  float* z8 = ws + AR1;
  float* a9 = ws + AR1 + 1775616;
  float* y2 = ws + AR0;
  float* y3 = ws + AR0 + 5849088;
  float* y4 = ws + AR0;
  float* y5 = ws + AR0 + 2088960;
  float* y6 = ws + AR0;
  float* y7 = ws + AR0 + 626688;
  float* y8 = ws + AR0 + 1253376;
  float* y9 = ws + AR0;
  float* y10 = ws + AR0 + 104448;
  short* apk2 = (short*)(ws + 12000000);    // 7*2*64*512 = 458752 sh
  short* apk3 = apk2 + 7 * 2 * 64 * 512;    // 7*2*64*256 = 229376 sh
  short* apk4 = apk3 + 7 * 2 * 64 * 256;    // 5*2*128*512 = 655360 sh
  short* apk5 = apk4 + 5 * 2 * 128 * 512;   // 5*2*128*512 = 655360 sh
  float* st[11];
  for (int i = 1; i <= 10; ++i) st[i] = ws + STATS + (size_t)(i - 1) * 1024;

  hipMemsetAsync((void*)(ws + STATS), 0, 10 * 1024 * sizeof(float), stream);

  // ---- pad x, pack w1, MFMA lift (+ split stats1 pass)
  pad_x_kernel<<<(8 * PROW + 255) / 256, 256, 0, stream>>>(x, xpad);
  pack_w1_kernel<<<(9 * 64 * 96 + 255) / 256, 256, 0, stream>>>(w1, apk1);
  lift_mfma_kernel<<<dim3(512, 9, 8), 256, 0, stream>>>(xpad, apk1, y1);
  stats_kernel<<<dim3(51, 8, 8), 256, 0, stream>>>(y1, st[1], 51, 9 * 8192, 8);
  {
    unsigned int tot = 8u * 51 * 9 * 2048;
    bnrelu_pool_bf16_kernel<<<(tot + 255) / 256, 256, 0, stream>>>(
        y1, st[1], gg[1], bbv[1], z1b, 51, 9, 8192, 1.f / 589824.f, tot);
  }
  // ---- per-s weight packs (KPAD = multiple of 256)
  pack_w2_kernel<<<(7 * 64 * 512 + 255) / 256, 256, 0, stream>>>(
      w2, apk2, 51, 459, 512, 64, 7, 9);
  pack_w2_kernel<<<(7 * 64 * 256 + 255) / 256, 256, 0, stream>>>(
      w3, apk3, 51, 153, 256, 64, 7, 3);
  pack_w2_kernel<<<(5 * 128 * 512 + 255) / 256, 256, 0, stream>>>(
      w4, apk4, 102, 459, 512, 128, 5, 9);
  pack_w2_kernel<<<(5 * 128 * 512 + 255) / 256, 256, 0, stream>>>(
      w5, apk5, 102, 306, 512, 128, 5, 3);
  // ---- gg2: 51->51, H 9->7, L=2048 (2 barrier-pairs)
  gg_mfma6_kernel<3, 64><<<dim3(32, 7, 8), 256, 0, stream>>>(
      z1b, apk2, y2, st[2], 51, 51, 9, 2048, 32, 459, 512, 64);
  {
    unsigned int tot = 8u * 51 * 7 * 2048;
    bnrelu_bf16_kernel<<<(tot + 255) / 256, 256, 0, stream>>>(
        y2, st[2], gg[2], bbv[2], a3b, 51, 7 * 2048, 1.f / 114688.f, tot);
  }
  // ---- gg3: 51->51, H7, L=2048 (single pass)
  gg_mfma6_kernel<1, 64><<<dim3(32, 7, 8), 256, 0, stream>>>(
      a3b, apk3, y3, st[3], 51, 51, 7, 2048, 32, 153, 256, 64);
  {
    unsigned int tot = 8u * 51 * 7 * 512;
    bnrelu_pool_bf16_kernel<<<(tot + 255) / 256, 256, 0, stream>>>(
        y3, st[3], gg[3], bbv[3], z3b, 51, 7, 2048, 1.f / 114688.f, tot);
  }
  // ---- gg4: 51->102, H 7->5, L=512
  gg_mfma6_kernel<3, 32><<<dim3(32, 5, 8), 256, 0, stream>>>(
      z3b, apk4, y4, st[4], 51, 102, 7, 512, 16, 459, 512, 128);
  {
    unsigned int tot = 8u * 102 * 5 * 512;
    bnrelu_bf16_kernel<<<(tot + 255) / 256, 256, 0, stream>>>(
        y4, st[4], gg[4], bbv[4], a5b, 102, 5 * 512, 1.f / 20480.f, tot);
  }
  // ---- gg5: 102->102, H5, L=512
  gg_mfma6_kernel<1, 32><<<dim3(32, 5, 8), 256, 0, stream>>>(
      a5b, apk5, y5, st[5], 102, 102, 5, 512, 16, 306, 512, 128);
  {
    unsigned int tot = 8u * 102 * 5 * 128;
    bnrelu_pool_kernel<<<(tot + 255) / 256, 256, 0, stream>>>(
        y5, st[5], gg[5], bbv[5], z5, 102, 5, 512, 1.f / 20480.f, tot);
  }
  // ---- gg6/7/8: K-split x3 tails
  hipMemsetAsync((void*)y6, 0, 3 * 626688 * sizeof(float), stream);
  gg_tail2_kernel<3, 128, 2><<<dim3(102, 9, 8), 256, 0, stream>>>(
      z5, w6, y6, 102, 204, 5, 3, 34);
  stats_kernel<<<dim3(204, 8, 1), 256, 0, stream>>>(y6, st[6], 204, 384, 1);
  {
    unsigned int tot = 8u * 204 * 3 * 128;
    bnrelu_kernel<<<(tot + 255) / 256, 256, 0, stream>>>(
        y6, st[6], gg[6], bbv[6], a6, 204, 3 * 128, 1.f / 3072.f, tot);
  }
  gg_tail2_kernel<1, 128, 2><<<dim3(102, 9, 8), 256, 0, stream>>>(
      a6, w7, y7, 204, 204, 3, 3, 68);
  stats_kernel<<<dim3(204, 8, 1), 256, 0, stream>>>(y7, st[7], 204, 384, 1);
  {
    unsigned int tot = 8u * 204 * 3 * 128;
    bnrelu_kernel<<<(tot + 255) / 256, 256, 0, stream>>>(
        y7, st[7], gg[7], bbv[7], a7, 204, 3 * 128, 1.f / 3072.f, tot);
  }
  gg_tail2_kernel<1, 128, 2><<<dim3(102, 9, 8), 256, 0, stream>>>(
      a7, w8, y8, 204, 204, 3, 3, 68);
  stats_kernel<<<dim3(204, 8, 1), 256, 0, stream>>>(y8, st[8], 204, 384, 1);
  {
    unsigned int tot = 8u * 204 * 3 * 32;
    bnrelu_pool_kernel<<<(tot + 255) / 256, 256, 0, stream>>>(
        y8, st[8], gg[8], bbv[8], z8, 204, 3, 128, 1.f / 3072.f, tot);
  }
  // ---- gg9: 204->408, H 3->1, L=32 (K-split x4)
  hipMemsetAsync((void*)y9, 0, 2 * 104448 * sizeof(float), stream);
  gg_tail2_kernel<3, 32, 8><<<dim3(51, 4, 8), 256, 0, stream>>>(
      z8, w9, y9, 204, 408, 3, 4, 51);
  stats_kernel<<<dim3(408, 8, 1), 256, 0, stream>>>(y9, st[9], 408, 32, 1);
  {
    unsigned int tot = 8u * 408 * 32;
    bnrelu_kernel<<<(tot + 255) / 256, 256, 0, stream>>>(
        y9, st[9], gg[9], bbv[9], a9, 408, 32, 1.f / 256.f, tot);
  }
  // ---- gg10: 408->408, H1, L=32 (K-split x4)
  gg_tail2_kernel<1, 32, 8><<<dim3(51, 4, 8), 256, 0, stream>>>(
      a9, w10, y10, 408, 408, 1, 4, 102);
  stats_kernel<<<dim3(408, 8, 1), 256, 0, stream>>>(y10, st[10], 408, 32, 1);
  // ---- final
  final_kernel<<<dim3(8), 256, 0, stream>>>(y10, st[10], gg[10], bbv[10], w11,
                                            (float*)d_out);
}

// Round 15
// 1040.065 us; speedup vs baseline: 1.3460x; 1.3460x over previous
//
#include <hip/hip_runtime.h>
#include <hip/hip_bf16.h>

#define EPSBN 2e-5f

typedef __attribute__((ext_vector_type(8))) short short8v;
typedef __attribute__((ext_vector_type(4))) float f32x4;

__device__ inline unsigned short f2bf(float f) {
  unsigned u = __float_as_uint(f);
  unsigned r = (u + 0x7FFFu + ((u >> 16) & 1u)) >> 16;
  return (unsigned short)r;
}
__device__ inline float bf2f(unsigned short h) {
  return __uint_as_float(((unsigned)h) << 16);
}

// ---------------------------------------------------------------------------
// Padded x staging
// ---------------------------------------------------------------------------
constexpr int XPADL = 9984;
constexpr int XPADR = 14336;
constexpr int PROW = XPADL + 32768 + XPADR;  // 57088

__global__ __launch_bounds__(256) void pad_x_kernel(const float* __restrict__ x,
                                                    float* __restrict__ xp) {
  int i = blockIdx.x * 256 + threadIdx.x;
  if (i >= 8 * PROW) return;
  int b = i / PROW;
  int pos = i - b * PROW - XPADL;
  xp[i] = (pos >= 0 && pos < 32768) ? x[b * 32768 + pos] : 0.f;
}

// ---------------------------------------------------------------------------
// Pack w1 [51][79] -> per-s split bf16 (1/2^s folded), [s][hi/lo][64][96]
// ---------------------------------------------------------------------------
__global__ __launch_bounds__(256) void pack_w1_kernel(
    const float* __restrict__ W, short* __restrict__ A) {
  int idx = blockIdx.x * 256 + threadIdx.x;
  if (idx >= 9 * 64 * 96) return;
  int s = idx / (64 * 96);
  int rem = idx - s * 64 * 96;
  int co = rem / 96;
  int k = rem - co * 96;
  float v = 0.f;
  if (co < 51 && k < 79)
    v = W[co * 79 + k] * __uint_as_float((unsigned)(127 - s) << 23);
  unsigned short hi = f2bf(v);
  unsigned short lo = f2bf(v - bf2f(hi));
  A[(size_t)s * 2 * 64 * 96 + co * 96 + k] = (short)hi;
  A[(size_t)s * 2 * 64 * 96 + 64 * 96 + co * 96 + k] = (short)lo;
}

// ---------------------------------------------------------------------------
// lift_mfma: lift conv K=79 as bf16 MFMA GEMM + fused pool4 (R12, unchanged)
// ---------------------------------------------------------------------------
__global__ __launch_bounds__(256) void lift_mfma_kernel(
    const float* __restrict__ xp, const short* __restrict__ Apk1,
    float* __restrict__ y1) {
  constexpr int P = 104;
  const int lc = blockIdx.x;
  const int s = blockIdx.y;
  const int b = blockIdx.z;
  const int d = 1 << s;
  const int l0 = lc * 64;
  const int tid = threadIdx.x;
  const int lane = tid & 63;
  const int quad = lane >> 4;
  const int n0 = lane & 15;
  const int wv = tid >> 6;
  const int coBase = wv * 16;

  __shared__ __align__(16) short Bh[64 * P];
  __shared__ __align__(16) short Bl[64 * P];

  const float* xrow = xp + b * PROW + XPADL;

  const int nB = tid & 63;
  const int og = tid >> 6;
#pragma unroll
  for (int r = 0; r < 3; ++r) {
    const int oct = og + 4 * r;
    const int kb = oct * 8;
    float v[8];
#pragma unroll
    for (int j = 0; j < 8; ++j) v[j] = xrow[l0 + nB + (kb + j - 39) * d];
    unsigned h[8], lo[8];
#pragma unroll
    for (int j = 0; j < 8; ++j) {
      unsigned u = __float_as_uint(v[j]);
      h[j] = u >> 16;
      float lof = v[j] - __uint_as_float(u & 0xffff0000u);
      lo[j] = __float_as_uint(lof) >> 16;
    }
    uint4 ph, pl;
    ph.x = h[0] | (h[1] << 16);
    ph.y = h[2] | (h[3] << 16);
    ph.z = h[4] | (h[5] << 16);
    ph.w = h[6] | (h[7] << 16);
    pl.x = lo[0] | (lo[1] << 16);
    pl.y = lo[2] | (lo[3] << 16);
    pl.z = lo[4] | (lo[5] << 16);
    pl.w = lo[6] | (lo[7] << 16);
    *(uint4*)(Bh + nB * P + kb) = ph;
    *(uint4*)(Bl + nB * P + kb) = pl;
  }

  const short* ApkS = Apk1 + (size_t)s * 2 * 64 * 96;
  const short* arowH = ApkS + (coBase + n0) * 96;
  const short* arowL = arowH + 64 * 96;

  __syncthreads();

  f32x4 acc[4];
#pragma unroll
  for (int t = 0; t < 4; ++t) acc[t] = (f32x4){0.f, 0.f, 0.f, 0.f};

#pragma unroll
  for (int ks = 0; ks < 3; ++ks) {
    short8v ah = *(const short8v*)(arowH + ks * 32 + quad * 8);
    short8v al = *(const short8v*)(arowL + ks * 32 + quad * 8);
#pragma unroll
    for (int t = 0; t < 4; ++t) {
      const int n = n0 + 16 * t;
      short8v bh = *(const short8v*)(Bh + n * P + ks * 32 + quad * 8);
      short8v bl = *(const short8v*)(Bl + n * P + ks * 32 + quad * 8);
      acc[t] = __builtin_amdgcn_mfma_f32_16x16x32_bf16(ah, bh, acc[t], 0, 0, 0);
      acc[t] = __builtin_amdgcn_mfma_f32_16x16x32_bf16(ah, bl, acc[t], 0, 0, 0);
      acc[t] = __builtin_amdgcn_mfma_f32_16x16x32_bf16(al, bh, acc[t], 0, 0, 0);
    }
  }

#pragma unroll
  for (int reg = 0; reg < 4; ++reg) {
    const int co = coBase + quad * 4 + reg;
#pragma unroll
    for (int t = 0; t < 4; ++t) {
      float u = acc[t][reg];
      u = fmaxf(u, __shfl_xor(u, 1));
      u = fmaxf(u, __shfl_xor(u, 2));
      if ((n0 & 3) == 0 && co < 51) {
        const int l1 = (l0 >> 2) + t * 4 + (n0 >> 2);
        y1[(((size_t)b * 51 + co) * 9 + s) * 8192 + l1] = u;
      }
    }
  }
}

// ---------------------------------------------------------------------------
// Per-channel sum/sumsq over [B,C,HL], HL split NS ways; grid (C,B,NS)
// ---------------------------------------------------------------------------
__global__ __launch_bounds__(256) void stats_kernel(
    const float* __restrict__ Y, float* __restrict__ st, int C, int HL,
    int NS) {
  const int c = blockIdx.x, b = blockIdx.y, z = blockIdx.z;
  const int slice = HL / NS;
  const float* p = Y + ((size_t)b * C + c) * HL + (size_t)z * slice;
  float s = 0.f, q = 0.f;
  for (int i = threadIdx.x; i < slice; i += 256) {
    float v = p[i];
    s += v;
    q += v * v;
  }
#pragma unroll
  for (int off = 32; off > 0; off >>= 1) {
    s += __shfl_down(s, off, 64);
    q += __shfl_down(q, off, 64);
  }
  __shared__ float ls[4], lq[4];
  const int wid = threadIdx.x >> 6, lane = threadIdx.x & 63;
  if (lane == 0) { ls[wid] = s; lq[wid] = q; }
  __syncthreads();
  if (threadIdx.x == 0) {
    atomicAdd(&st[c], ls[0] + ls[1] + ls[2] + ls[3]);
    atomicAdd(&st[512 + c], lq[0] + lq[1] + lq[2] + lq[3]);
  }
}

// ---------------------------------------------------------------------------
// BN(train)+ReLU+pool4, fp32 out
// ---------------------------------------------------------------------------
__global__ __launch_bounds__(256) void bnrelu_pool_kernel(
    const float* __restrict__ Y, const float* __restrict__ st,
    const float* __restrict__ g, const float* __restrict__ bb,
    float* __restrict__ Z, int C, int H, int Lin, float invN,
    unsigned int total) {
  unsigned int idx = blockIdx.x * 256u + threadIdx.x;
  if (idx >= total) return;
  const unsigned int Lo = (unsigned int)(Lin >> 2);
  unsigned int lo = idx % Lo;
  unsigned int r1 = idx / Lo;
  unsigned int h = r1 % (unsigned int)H;
  unsigned int r2 = r1 / (unsigned int)H;
  unsigned int c = r2 % (unsigned int)C;
  unsigned int b = r2 / (unsigned int)C;
  float m = st[c] * invN;
  float v = st[512 + c] * invN - m * m;
  float sc = g[c] * rsqrtf(v + EPSBN);
  float bi = bb[c] - m * sc;
  const float* p = Y + (((size_t)b * C + c) * H + h) * Lin + 4u * lo;
  float a0 = p[0] * sc + bi, a1 = p[1] * sc + bi;
  float a2 = p[2] * sc + bi, a3 = p[3] * sc + bi;
  float r = fmaxf(fmaxf(a0, a1), fmaxf(a2, a3));
  Z[idx] = fmaxf(r, 0.f);
}

// ---- same, bf16 out
__global__ __launch_bounds__(256) void bnrelu_pool_bf16_kernel(
    const float* __restrict__ Y, const float* __restrict__ st,
    const float* __restrict__ g, const float* __restrict__ bb,
    unsigned short* __restrict__ Z, int C, int H, int Lin, float invN,
    unsigned int total) {
  unsigned int idx = blockIdx.x * 256u + threadIdx.x;
  if (idx >= total) return;
  const unsigned int Lo = (unsigned int)(Lin >> 2);
  unsigned int lo = idx % Lo;
  unsigned int r1 = idx / Lo;
  unsigned int h = r1 % (unsigned int)H;
  unsigned int r2 = r1 / (unsigned int)H;
  unsigned int c = r2 % (unsigned int)C;
  unsigned int b = r2 / (unsigned int)C;
  float m = st[c] * invN;
  float v = st[512 + c] * invN - m * m;
  float sc = g[c] * rsqrtf(v + EPSBN);
  float bi = bb[c] - m * sc;
  const float* p = Y + (((size_t)b * C + c) * H + h) * Lin + 4u * lo;
  float a0 = p[0] * sc + bi, a1 = p[1] * sc + bi;
  float a2 = p[2] * sc + bi, a3 = p[3] * sc + bi;
  float r = fmaxf(fmaxf(a0, a1), fmaxf(a2, a3));
  Z[idx] = f2bf(fmaxf(r, 0.f));
}

// ---------------------------------------------------------------------------
// BN(train)+ReLU elementwise, fp32 / bf16 out
// ---------------------------------------------------------------------------
__global__ __launch_bounds__(256) void bnrelu_kernel(
    const float* __restrict__ Y, const float* __restrict__ st,
    const float* __restrict__ g, const float* __restrict__ bb,
    float* __restrict__ A, int C, int HL, float invN, unsigned int total) {
  unsigned int idx = blockIdx.x * 256u + threadIdx.x;
  if (idx >= total) return;
  unsigned int c = (idx / (unsigned int)HL) % (unsigned int)C;
  float m = st[c] * invN;
  float v = st[512 + c] * invN - m * m;
  float sc = g[c] * rsqrtf(v + EPSBN);
  float bi = bb[c] - m * sc;
  A[idx] = fmaxf(fmaf(Y[idx], sc, bi), 0.f);
}

__global__ __launch_bounds__(256) void bnrelu_bf16_kernel(
    const float* __restrict__ Y, const float* __restrict__ st,
    const float* __restrict__ g, const float* __restrict__ bb,
    unsigned short* __restrict__ A, int C, int HL, float invN,
    unsigned int total) {
  unsigned int idx = blockIdx.x * 256u + threadIdx.x;
  if (idx >= total) return;
  unsigned int c = (idx / (unsigned int)HL) % (unsigned int)C;
  float m = st[c] * invN;
  float v = st[512 + c] * invN - m * m;
  float sc = g[c] * rsqrtf(v + EPSBN);
  float bi = bb[c] - m * sc;
  A[idx] = f2bf(fmaxf(fmaf(Y[idx], sc, bi), 0.f));
}

// ---------------------------------------------------------------------------
// Pack fp32 weights -> per-s split bf16 packs with 2^-(s+i) folded.
// ---------------------------------------------------------------------------
__global__ __launch_bounds__(256) void pack_w2_kernel(
    const float* __restrict__ W, short* __restrict__ A, int Co, int KTOT,
    int KPAD, int COPAD, int NS, int nk3) {
  int idx = blockIdx.x * 256 + threadIdx.x;
  const int CK = COPAD * KPAD;
  if (idx >= NS * CK) return;
  int s = idx / CK;
  int rem = idx - s * CK;
  int co = rem / KPAD;
  int kk = rem - co * KPAD;
  float v = 0.f;
  if (co < Co && kk < KTOT) {
    int i = (kk % nk3) / 3;
    float scale = __uint_as_float((unsigned)(127 - (s + i)) << 23);
    v = W[co * KTOT + kk] * scale;
  }
  unsigned short hi = f2bf(v);
  unsigned short lo = f2bf(v - bf2f(hi));
  A[(size_t)s * 2 * CK + co * KPAD + kk] = (short)hi;
  A[(size_t)s * 2 * CK + CK + co * KPAD + kk] = (short)lo;
}

// ---------------------------------------------------------------------------
// gg_mfma5: bf16-input, depth-2 register-prefetch MFMA GConvGG (R13 core),
// WITHOUT fused stats (the 229k contended stats atomics were the real
// ~150 us bottleneck across R8-R14 — stats now run as a separate pass).
// ---------------------------------------------------------------------------
template <int NKv, int LT>
__global__ __launch_bounds__(256) void gg_mfma5_kernel(
    const unsigned short* __restrict__ X, const short* __restrict__ Apk,
    float* __restrict__ Y, int Ci, int Co, int Hin, int L, int nL, int KTOT,
    int KPAD, int COPAD) {
  constexpr int T = LT / 16;
  constexpr int KO = 256 / LT;
  constexpr int RIT = 8 / KO;

  const int bx = blockIdx.x;
  const int lc = bx % nL;
  const int cog = bx / nL;
  const int s = blockIdx.y;
  const int b = blockIdx.z;
  const int Hout = Hin - NKv + 1;
  const int l0 = lc * LT;
  const int tid = threadIdx.x;
  const int lane = tid & 63;
  const int quad = lane >> 4;
  const int m0 = lane & 15;
  const int wv = tid >> 6;
  const int coBase = cog * 64 + wv * 16;

  __shared__ __align__(16) short Bh[LT * 72];
  __shared__ int roT[512];
  __shared__ int shT[512];

  for (int kk = tid; kk < KPAD; kk += 256) {
    int ro = 0, sh = -(1 << 30);
    if (kk < KTOT) {
      int ci = kk / (3 * NKv);
      int rem = kk - ci * (3 * NKv);
      int i = rem / 3;
      int k = rem - 3 * i;
      ro = (ci * Hin + s + i) * L;
      sh = (k - 1) * (1 << (s + i));
    }
    roT[kk] = ro;
    shT[kk] = sh;
  }
  __syncthreads();

  f32x4 acc[T];
#pragma unroll
  for (int t = 0; t < T; ++t) acc[t] = (f32x4){0.f, 0.f, 0.f, 0.f};

  const short* ApkS = Apk + (size_t)s * 2 * COPAD * KPAD;
  const short* arowH = ApkS + (size_t)(coBase + m0) * KPAD;
  const short* arowL = arowH + (size_t)COPAD * KPAD;
  const unsigned short* Xb = X + (size_t)b * Ci * Hin * L;

  const int lB = tid & (LT - 1);
  const int oc0 = tid / LT;
  const int nch = (KTOT + 63) >> 6;

  uint4 v0[RIT], v1[RIT], v2[RIT];
  auto gather = [&](int c0, uint4 (&pk)[RIT]) {
#pragma unroll
    for (int r = 0; r < RIT; ++r) {
      const int oct = oc0 + KO * r;
      const int kkb = (c0 << 6) + oct * 8;
      unsigned w[8];
#pragma unroll
      for (int j = 0; j < 8; ++j) {
        const int kk = kkb + j;
        const int pos = l0 + lB + shT[kk];
        const int posc = min(max(pos, 0), L - 1);
        unsigned u = (unsigned)Xb[roT[kk] + posc];
        w[j] = ((unsigned)pos < (unsigned)L) ? u : 0u;
      }
      pk[r].x = w[0] | (w[1] << 16);
      pk[r].y = w[2] | (w[3] << 16);
      pk[r].z = w[4] | (w[5] << 16);
      pk[r].w = w[6] | (w[7] << 16);
    }
  };

  gather(0, v0);
  if (nch > 1) gather(1, v1);
  for (int c0 = 0; c0 < nch; ++c0) {
#pragma unroll
    for (int r = 0; r < RIT; ++r)
      *(uint4*)(Bh + lB * 72 + (oc0 + KO * r) * 8) = v0[r];
    if (c0 + 2 < nch) gather(c0 + 2, v2);
    const int a0 = (c0 << 6) + quad * 8;
    short8v ah0 = *(const short8v*)(arowH + a0);
    short8v al0 = *(const short8v*)(arowL + a0);
    short8v ah1 = *(const short8v*)(arowH + a0 + 32);
    short8v al1 = *(const short8v*)(arowL + a0 + 32);
    __syncthreads();
#pragma unroll
    for (int t = 0; t < T; ++t) {
      const int l = m0 + 16 * t;
      short8v b0 = *(const short8v*)(Bh + l * 72 + quad * 8);
      short8v b1 = *(const short8v*)(Bh + l * 72 + 32 + quad * 8);
      acc[t] = __builtin_amdgcn_mfma_f32_16x16x32_bf16(ah0, b0, acc[t], 0, 0, 0);
      acc[t] = __builtin_amdgcn_mfma_f32_16x16x32_bf16(al0, b0, acc[t], 0, 0, 0);
      acc[t] = __builtin_amdgcn_mfma_f32_16x16x32_bf16(ah1, b1, acc[t], 0, 0, 0);
      acc[t] = __builtin_amdgcn_mfma_f32_16x16x32_bf16(al1, b1, acc[t], 0, 0, 0);
    }
    __syncthreads();
#pragma unroll
    for (int r = 0; r < RIT; ++r) {
      v0[r] = v1[r];
      v1[r] = v2[r];
    }
  }

  // ---- epilogue: plain stores only (no atomics)
#pragma unroll
  for (int reg = 0; reg < 4; ++reg) {
    const int co = coBase + quad * 4 + reg;
    if (co < Co) {
      float* yp = Y + (((size_t)b * Co + co) * Hout + s) * L + l0;
#pragma unroll
      for (int t = 0; t < T; ++t) yp[m0 + 16 * t] = acc[t][reg];
    }
  }
}

// ---------------------------------------------------------------------------
// gg_tail2: K-split no-LDS GConvGG (input pre-activated fp32).
// ---------------------------------------------------------------------------
template <int NK, int L, int COSUB>
__global__ __launch_bounds__(256) void gg_tail2_kernel(
    const float* __restrict__ X, const float* __restrict__ W,
    float* __restrict__ Y, int Ci, int Co, int Hin, int NSPLIT, int ciPer) {
  const int l = threadIdx.x % L;
  const int cs = threadIdx.x / L;
  const int co = blockIdx.x * COSUB + cs;
  const int s = blockIdx.y / NSPLIT;
  const int seg = blockIdx.y % NSPLIT;
  const int b = blockIdx.z;
  const int Hout = Hin - NK + 1;
  const int ciBeg = seg * ciPer;
  const int ciEnd = min(Ci, ciBeg + ciPer);

  float acc[NK];
#pragma unroll
  for (int i = 0; i < NK; ++i) acc[i] = 0.f;

  const float* wbase = W + (size_t)co * Ci * NK * 3;
  const float* xbase = X + ((size_t)b * Ci * Hin + s) * L;

  for (int ci = ciBeg; ci < ciEnd; ++ci) {
    const float* wp = wbase + ci * (NK * 3);
    const float* xr = xbase + ci * (Hin * L);
#pragma unroll
    for (int i = 0; i < NK; ++i) {
      const int d = 1 << (s + i);
      const float* row = xr + i * L;
      float xm = (l >= d) ? row[l - d] : 0.f;
      float xc = row[l];
      float xp = (l + d < L) ? row[l + d] : 0.f;
      acc[i] = fmaf(wp[3 * i], xm,
                    fmaf(wp[3 * i + 1], xc, fmaf(wp[3 * i + 2], xp, acc[i])));
    }
  }
  float out = 0.f;
#pragma unroll
  for (int i = 0; i < NK; ++i) {
    float invd = __uint_as_float((unsigned)(127 - (s + i)) << 23);
    out = fmaf(acc[i], invd, out);
  }
  atomicAdd(&Y[(((size_t)b * Co + co) * Hout + s) * L + l], out);
}

// ---------------------------------------------------------------------------
// Final: bn10+relu, mean over L, classifier
// ---------------------------------------------------------------------------
__global__ __launch_bounds__(256) void final_kernel(
    const float* __restrict__ Y, const float* __restrict__ st,
    const float* __restrict__ g, const float* __restrict__ bb,
    const float* __restrict__ w11, float* __restrict__ out) {
  const int b = blockIdx.x;
  const int tid = threadIdx.x;
  __shared__ float tch[408];
  for (int c = tid; c < 408; c += 256) {
    float m = st[c] * (1.f / 256.f);
    float v = st[512 + c] * (1.f / 256.f) - m * m;
    float sc = g[c] * rsqrtf(v + EPSBN);
    float bi = bb[c] - m * sc;
    const float* p = Y + ((size_t)b * 408 + c) * 32;
    float ssum = 0.f;
#pragma unroll
    for (int l = 0; l < 32; ++l) ssum += fmaxf(p[l] * sc + bi, 0.f);
    tch[c] = ssum * (1.f / 32.f);
  }
  __syncthreads();
  if (tid < 10) {
    float ssum = 0.f;
    for (int c = 0; c < 408; ++c) ssum += w11[tid * 408 + c] * tch[c];
    out[b * 10 + tid] = ssum;
  }
}

// ---------------------------------------------------------------------------
extern "C" void kernel_launch(void* const* d_in, const int* in_sizes, int n_in,
                              void* d_out, int out_size, void* d_ws,
                              size_t ws_size, hipStream_t stream) {
  const float* x = (const float*)d_in[0];
  const float* w1 = (const float*)d_in[1];
  const float* w2 = (const float*)d_in[2];
  const float* w3 = (const float*)d_in[3];
  const float* w4 = (const float*)d_in[4];
  const float* w5 = (const float*)d_in[5];
  const float* w6 = (const float*)d_in[6];
  const float* w7 = (const float*)d_in[7];
  const float* w8 = (const float*)d_in[8];
  const float* w9 = (const float*)d_in[9];
  const float* w10 = (const float*)d_in[10];
  const float* w11 = (const float*)d_in[11];
  const float* gg[11];
  const float* bbv[11];
  for (int i = 1; i <= 10; ++i) {
    gg[i] = (const float*)d_in[12 + 2 * (i - 1)];
    bbv[i] = (const float*)d_in[12 + 2 * (i - 1) + 1];
  }

  float* ws = (float*)d_ws;
  const size_t AR0 = 0;
  const size_t AR1 = 30081024;
  const size_t STATS = 37601280;
  float* y1 = ws + AR0;
  float* xpad = ws + AR1;
  short* apk1 = (short*)(ws + AR1 + 460800);
  unsigned short* z1b = (unsigned short*)(ws + AR1);
  unsigned short* a3b = (unsigned short*)(ws + AR1);
  unsigned short* z3b = (unsigned short*)(ws + AR1);
  unsigned short* a5b = (unsigned short*)(ws + AR1 + 1500000);
  float* z5 = ws + AR1;
  float* a6 = ws + AR1 + 522240;
  float* a7 = ws + AR1 + 1148928;
  float* z8 = ws + AR1;
  float* a9 = ws + AR1 + 1775616;
  float* y2 = ws + AR0;
  float* y3 = ws + AR0 + 5849088;
  float* y4 = ws + AR0;
  float* y5 = ws + AR0 + 2088960;
  float* y6 = ws + AR0;
  float* y7 = ws + AR0 + 626688;
  float* y8 = ws + AR0 + 1253376;
  float* y9 = ws + AR0;
  float* y10 = ws + AR0 + 104448;
  short* apk2 = (short*)(ws + 12000000);
  short* apk3 = apk2 + 7 * 2 * 64 * 512;
  short* apk4 = apk3 + 7 * 2 * 64 * 192;
  short* apk5 = apk4 + 5 * 2 * 128 * 512;
  float* st[11];
  for (int i = 1; i <= 10; ++i) st[i] = ws + STATS + (size_t)(i - 1) * 1024;

  hipMemsetAsync((void*)(ws + STATS), 0, 10 * 1024 * sizeof(float), stream);

  // ---- pad x, pack w1, MFMA lift (+ split stats1 pass)
  pad_x_kernel<<<(8 * PROW + 255) / 256, 256, 0, stream>>>(x, xpad);
  pack_w1_kernel<<<(9 * 64 * 96 + 255) / 256, 256, 0, stream>>>(w1, apk1);
  lift_mfma_kernel<<<dim3(512, 9, 8), 256, 0, stream>>>(xpad, apk1, y1);
  stats_kernel<<<dim3(51, 8, 8), 256, 0, stream>>>(y1, st[1], 51, 9 * 8192, 8);
  {
    unsigned int tot = 8u * 51 * 9 * 2048;
    bnrelu_pool_bf16_kernel<<<(tot + 255) / 256, 256, 0, stream>>>(
        y1, st[1], gg[1], bbv[1], z1b, 51, 9, 8192, 1.f / 589824.f, tot);
  }
  // ---- per-s weight packs
  pack_w2_kernel<<<(7 * 64 * 512 + 255) / 256, 256, 0, stream>>>(
      w2, apk2, 51, 459, 512, 64, 7, 9);
  pack_w2_kernel<<<(7 * 64 * 192 + 255) / 256, 256, 0, stream>>>(
      w3, apk3, 51, 153, 192, 64, 7, 3);
  pack_w2_kernel<<<(5 * 128 * 512 + 255) / 256, 256, 0, stream>>>(
      w4, apk4, 102, 459, 512, 128, 5, 9);
  pack_w2_kernel<<<(5 * 128 * 320 + 255) / 256, 256, 0, stream>>>(
      w5, apk5, 102, 306, 320, 128, 5, 3);
  // ---- gg2: 51->51, H 9->7, L=2048 (stats via separate pass)
  gg_mfma5_kernel<3, 64><<<dim3(32, 7, 8), 256, 0, stream>>>(
      z1b, apk2, y2, 51, 51, 9, 2048, 32, 459, 512, 64);
  stats_kernel<<<dim3(51, 8, 4), 256, 0, stream>>>(y2, st[2], 51, 7 * 2048, 4);
  {
    unsigned int tot = 8u * 51 * 7 * 2048;
    bnrelu_bf16_kernel<<<(tot + 255) / 256, 256, 0, stream>>>(
        y2, st[2], gg[2], bbv[2], a3b, 51, 7 * 2048, 1.f / 114688.f, tot);
  }
  // ---- gg3: 51->51, H7, L=2048
  gg_mfma5_kernel<1, 64><<<dim3(32, 7, 8), 256, 0, stream>>>(
      a3b, apk3, y3, 51, 51, 7, 2048, 32, 153, 192, 64);
  stats_kernel<<<dim3(51, 8, 4), 256, 0, stream>>>(y3, st[3], 51, 7 * 2048, 4);
  {
    unsigned int tot = 8u * 51 * 7 * 512;
    bnrelu_pool_bf16_kernel<<<(tot + 255) / 256, 256, 0, stream>>>(
        y3, st[3], gg[3], bbv[3], z3b, 51, 7, 2048, 1.f / 114688.f, tot);
  }
  // ---- gg4: 51->102, H 7->5, L=512
  gg_mfma5_kernel<3, 32><<<dim3(32, 5, 8), 256, 0, stream>>>(
      z3b, apk4, y4, 51, 102, 7, 512, 16, 459, 512, 128);
  stats_kernel<<<dim3(102, 8, 2), 256, 0, stream>>>(y4, st[4], 102, 5 * 512,
                                                    2);
  {
    unsigned int tot = 8u * 102 * 5 * 512;
    bnrelu_bf16_kernel<<<(tot + 255) / 256, 256, 0, stream>>>(
        y4, st[4], gg[4], bbv[4], a5b, 102, 5 * 512, 1.f / 20480.f, tot);
  }
  // ---- gg5: 102->102, H5, L=512
  gg_mfma5_kernel<1, 32><<<dim3(32, 5, 8), 256, 0, stream>>>(
      a5b, apk5, y5, 102, 102, 5, 512, 16, 306, 320, 128);
  stats_kernel<<<dim3(102, 8, 2), 256, 0, stream>>>(y5, st[5], 102, 5 * 512,
                                                    2);
  {
    unsigned int tot = 8u * 102 * 5 * 128;
    bnrelu_pool_kernel<<<(tot + 255) / 256, 256, 0, stream>>>(
        y5, st[5], gg[5], bbv[5], z5, 102, 5, 512, 1.f / 20480.f, tot);
  }
  // ---- gg6/7/8: K-split x3 tails
  hipMemsetAsync((void*)y6, 0, 3 * 626688 * sizeof(float), stream);
  gg_tail2_kernel<3, 128, 2><<<dim3(102, 9, 8), 256, 0, stream>>>(
      z5, w6, y6, 102, 204, 5, 3, 34);
  stats_kernel<<<dim3(204, 8, 1), 256, 0, stream>>>(y6, st[6], 204, 384, 1);
  {
    unsigned int tot = 8u * 204 * 3 * 128;
    bnrelu_kernel<<<(tot + 255) / 256, 256, 0, stream>>>(
        y6, st[6], gg[6], bbv[6], a6, 204, 3 * 128, 1.f / 3072.f, tot);
  }
  gg_tail2_kernel<1, 128, 2><<<dim3(102, 9, 8), 256, 0, stream>>>(
      a6, w7, y7, 204, 204, 3, 3, 68);
  stats_kernel<<<dim3(204, 8, 1), 256, 0, stream>>>(y7, st[7], 204, 384, 1);
  {
    unsigned int tot = 8u * 204 * 3 * 128;
    bnrelu_kernel<<<(tot + 255) / 256, 256, 0, stream>>>(
        y7, st[7], gg[7], bbv[7], a7, 204, 3 * 128, 1.f / 3072.f, tot);
  }
  gg_tail2_kernel<1, 128, 2><<<dim3(102, 9, 8), 256, 0, stream>>>(
      a7, w8, y8, 204, 204, 3, 3, 68);
  stats_kernel<<<dim3(204, 8, 1), 256, 0, stream>>>(y8, st[8], 204, 384, 1);
  {
    unsigned int tot = 8u * 204 * 3 * 32;
    bnrelu_pool_kernel<<<(tot + 255) / 256, 256, 0, stream>>>(
        y8, st[8], gg[8], bbv[8], z8, 204, 3, 128, 1.f / 3072.f, tot);
  }
  // ---- gg9: 204->408, H 3->1, L=32 (K-split x4)
  hipMemsetAsync((void*)y9, 0, 2 * 104448 * sizeof(float), stream);
  gg_tail2_kernel<3, 32, 8><<<dim3(51, 4, 8), 256, 0, stream>>>(
      z8, w9, y9, 204, 408, 3, 4, 51);
  stats_kernel<<<dim3(408, 8, 1), 256, 0, stream>>>(y9, st[9], 408, 32, 1);
  {
    unsigned int tot = 8u * 408 * 32;
    bnrelu_kernel<<<(tot + 255) / 256, 256, 0, stream>>>(
        y9, st[9], gg[9], bbv[9], a9, 408, 32, 1.f / 256.f, tot);
  }
  // ---- gg10: 408->408, H1, L=32 (K-split x4)
  gg_tail2_kernel<1, 32, 8><<<dim3(51, 4, 8), 256, 0, stream>>>(
      a9, w10, y10, 408, 408, 1, 4, 102);
  stats_kernel<<<dim3(408, 8, 1), 256, 0, stream>>>(y10, st[10], 408, 32, 1);
  // ---- final
  final_kernel<<<dim3(8), 256, 0, stream>>>(y10, st[10], gg[10], bbv[10], w11,
                                            (float*)d_out);
}

// Round 16
// 1030.945 us; speedup vs baseline: 1.3579x; 1.0088x over previous
//
#include <hip/hip_runtime.h>
#include <hip/hip_bf16.h>

#define EPSBN 2e-5f

typedef __attribute__((ext_vector_type(8))) short short8v;
typedef __attribute__((ext_vector_type(4))) float f32x4;

__device__ inline unsigned short f2bf(float f) {
  unsigned u = __float_as_uint(f);
  unsigned r = (u + 0x7FFFu + ((u >> 16) & 1u)) >> 16;
  return (unsigned short)r;
}
__device__ inline float bf2f(unsigned short h) {
  return __uint_as_float(((unsigned)h) << 16);
}

// ---------------------------------------------------------------------------
// Padded x staging
// ---------------------------------------------------------------------------
constexpr int XPADL = 9984;
constexpr int XPADR = 14336;
constexpr int PROW = XPADL + 32768 + XPADR;  // 57088

__global__ __launch_bounds__(256) void pad_x_kernel(const float* __restrict__ x,
                                                    float* __restrict__ xp) {
  int i = blockIdx.x * 256 + threadIdx.x;
  if (i >= 8 * PROW) return;
  int b = i / PROW;
  int pos = i - b * PROW - XPADL;
  xp[i] = (pos >= 0 && pos < 32768) ? x[b * 32768 + pos] : 0.f;
}

// ---------------------------------------------------------------------------
// Pack w1 [51][79] -> per-s split bf16 (1/2^s folded), [s][hi/lo][64][96]
// ---------------------------------------------------------------------------
__global__ __launch_bounds__(256) void pack_w1_kernel(
    const float* __restrict__ W, short* __restrict__ A) {
  int idx = blockIdx.x * 256 + threadIdx.x;
  if (idx >= 9 * 64 * 96) return;
  int s = idx / (64 * 96);
  int rem = idx - s * 64 * 96;
  int co = rem / 96;
  int k = rem - co * 96;
  float v = 0.f;
  if (co < 51 && k < 79)
    v = W[co * 79 + k] * __uint_as_float((unsigned)(127 - s) << 23);
  unsigned short hi = f2bf(v);
  unsigned short lo = f2bf(v - bf2f(hi));
  A[(size_t)s * 2 * 64 * 96 + co * 96 + k] = (short)hi;
  A[(size_t)s * 2 * 64 * 96 + 64 * 96 + co * 96 + k] = (short)lo;
}

// ---------------------------------------------------------------------------
// lift_mfma: lift conv K=79 as bf16 MFMA GEMM + fused pool4 (R12, unchanged)
// ---------------------------------------------------------------------------
__global__ __launch_bounds__(256) void lift_mfma_kernel(
    const float* __restrict__ xp, const short* __restrict__ Apk1,
    float* __restrict__ y1) {
  constexpr int P = 104;
  const int lc = blockIdx.x;
  const int s = blockIdx.y;
  const int b = blockIdx.z;
  const int d = 1 << s;
  const int l0 = lc * 64;
  const int tid = threadIdx.x;
  const int lane = tid & 63;
  const int quad = lane >> 4;
  const int n0 = lane & 15;
  const int wv = tid >> 6;
  const int coBase = wv * 16;

  __shared__ __align__(16) short Bh[64 * P];
  __shared__ __align__(16) short Bl[64 * P];

  const float* xrow = xp + b * PROW + XPADL;

  const int nB = tid & 63;
  const int og = tid >> 6;
#pragma unroll
  for (int r = 0; r < 3; ++r) {
    const int oct = og + 4 * r;
    const int kb = oct * 8;
    float v[8];
#pragma unroll
    for (int j = 0; j < 8; ++j) v[j] = xrow[l0 + nB + (kb + j - 39) * d];
    unsigned h[8], lo[8];
#pragma unroll
    for (int j = 0; j < 8; ++j) {
      unsigned u = __float_as_uint(v[j]);
      h[j] = u >> 16;
      float lof = v[j] - __uint_as_float(u & 0xffff0000u);
      lo[j] = __float_as_uint(lof) >> 16;
    }
    uint4 ph, pl;
    ph.x = h[0] | (h[1] << 16);
    ph.y = h[2] | (h[3] << 16);
    ph.z = h[4] | (h[5] << 16);
    ph.w = h[6] | (h[7] << 16);
    pl.x = lo[0] | (lo[1] << 16);
    pl.y = lo[2] | (lo[3] << 16);
    pl.z = lo[4] | (lo[5] << 16);
    pl.w = lo[6] | (lo[7] << 16);
    *(uint4*)(Bh + nB * P + kb) = ph;
    *(uint4*)(Bl + nB * P + kb) = pl;
  }

  const short* ApkS = Apk1 + (size_t)s * 2 * 64 * 96;
  const short* arowH = ApkS + (coBase + n0) * 96;
  const short* arowL = arowH + 64 * 96;

  __syncthreads();

  f32x4 acc[4];
#pragma unroll
  for (int t = 0; t < 4; ++t) acc[t] = (f32x4){0.f, 0.f, 0.f, 0.f};

#pragma unroll
  for (int ks = 0; ks < 3; ++ks) {
    short8v ah = *(const short8v*)(arowH + ks * 32 + quad * 8);
    short8v al = *(const short8v*)(arowL + ks * 32 + quad * 8);
#pragma unroll
    for (int t = 0; t < 4; ++t) {
      const int n = n0 + 16 * t;
      short8v bh = *(const short8v*)(Bh + n * P + ks * 32 + quad * 8);
      short8v bl = *(const short8v*)(Bl + n * P + ks * 32 + quad * 8);
      acc[t] = __builtin_amdgcn_mfma_f32_16x16x32_bf16(ah, bh, acc[t], 0, 0, 0);
      acc[t] = __builtin_amdgcn_mfma_f32_16x16x32_bf16(ah, bl, acc[t], 0, 0, 0);
      acc[t] = __builtin_amdgcn_mfma_f32_16x16x32_bf16(al, bh, acc[t], 0, 0, 0);
    }
  }

#pragma unroll
  for (int reg = 0; reg < 4; ++reg) {
    const int co = coBase + quad * 4 + reg;
#pragma unroll
    for (int t = 0; t < 4; ++t) {
      float u = acc[t][reg];
      u = fmaxf(u, __shfl_xor(u, 1));
      u = fmaxf(u, __shfl_xor(u, 2));
      if ((n0 & 3) == 0 && co < 51) {
        const int l1 = (l0 >> 2) + t * 4 + (n0 >> 2);
        y1[(((size_t)b * 51 + co) * 9 + s) * 8192 + l1] = u;
      }
    }
  }
}

// ---------------------------------------------------------------------------
// Per-channel sum/sumsq over [B,C,HL], HL split NS ways; grid (C,B,NS)
// ---------------------------------------------------------------------------
__global__ __launch_bounds__(256) void stats_kernel(
    const float* __restrict__ Y, float* __restrict__ st, int C, int HL,
    int NS) {
  const int c = blockIdx.x, b = blockIdx.y, z = blockIdx.z;
  const int slice = HL / NS;
  const float* p = Y + ((size_t)b * C + c) * HL + (size_t)z * slice;
  float s = 0.f, q = 0.f;
  for (int i = threadIdx.x; i < slice; i += 256) {
    float v = p[i];
    s += v;
    q += v * v;
  }
#pragma unroll
  for (int off = 32; off > 0; off >>= 1) {
    s += __shfl_down(s, off, 64);
    q += __shfl_down(q, off, 64);
  }
  __shared__ float ls[4], lq[4];
  const int wid = threadIdx.x >> 6, lane = threadIdx.x & 63;
  if (lane == 0) { ls[wid] = s; lq[wid] = q; }
  __syncthreads();
  if (threadIdx.x == 0) {
    atomicAdd(&st[c], ls[0] + ls[1] + ls[2] + ls[3]);
    atomicAdd(&st[512 + c], lq[0] + lq[1] + lq[2] + lq[3]);
  }
}

// ---------------------------------------------------------------------------
// reduce NS partial buffers: y[i] = sum_k p[k*stride + i]
// ---------------------------------------------------------------------------
__global__ __launch_bounds__(256) void reduce_parts_kernel(
    const float* __restrict__ p, float* __restrict__ y, int n, int stride,
    int ns) {
  int i = blockIdx.x * 256 + threadIdx.x;
  if (i >= n) return;
  float s = 0.f;
  for (int k = 0; k < ns; ++k) s += p[(size_t)k * stride + i];
  y[i] = s;
}

// ---------------------------------------------------------------------------
// BN(train)+ReLU+pool4, fp32 out
// ---------------------------------------------------------------------------
__global__ __launch_bounds__(256) void bnrelu_pool_kernel(
    const float* __restrict__ Y, const float* __restrict__ st,
    const float* __restrict__ g, const float* __restrict__ bb,
    float* __restrict__ Z, int C, int H, int Lin, float invN,
    unsigned int total) {
  unsigned int idx = blockIdx.x * 256u + threadIdx.x;
  if (idx >= total) return;
  const unsigned int Lo = (unsigned int)(Lin >> 2);
  unsigned int lo = idx % Lo;
  unsigned int r1 = idx / Lo;
  unsigned int h = r1 % (unsigned int)H;
  unsigned int r2 = r1 / (unsigned int)H;
  unsigned int c = r2 % (unsigned int)C;
  unsigned int b = r2 / (unsigned int)C;
  float m = st[c] * invN;
  float v = st[512 + c] * invN - m * m;
  float sc = g[c] * rsqrtf(v + EPSBN);
  float bi = bb[c] - m * sc;
  const float* p = Y + (((size_t)b * C + c) * H + h) * Lin + 4u * lo;
  float a0 = p[0] * sc + bi, a1 = p[1] * sc + bi;
  float a2 = p[2] * sc + bi, a3 = p[3] * sc + bi;
  float r = fmaxf(fmaxf(a0, a1), fmaxf(a2, a3));
  Z[idx] = fmaxf(r, 0.f);
}

// ---- same, bf16 out
__global__ __launch_bounds__(256) void bnrelu_pool_bf16_kernel(
    const float* __restrict__ Y, const float* __restrict__ st,
    const float* __restrict__ g, const float* __restrict__ bb,
    unsigned short* __restrict__ Z, int C, int H, int Lin, float invN,
    unsigned int total) {
  unsigned int idx = blockIdx.x * 256u + threadIdx.x;
  if (idx >= total) return;
  const unsigned int Lo = (unsigned int)(Lin >> 2);
  unsigned int lo = idx % Lo;
  unsigned int r1 = idx / Lo;
  unsigned int h = r1 % (unsigned int)H;
  unsigned int r2 = r1 / (unsigned int)H;
  unsigned int c = r2 % (unsigned int)C;
  unsigned int b = r2 / (unsigned int)C;
  float m = st[c] * invN;
  float v = st[512 + c] * invN - m * m;
  float sc = g[c] * rsqrtf(v + EPSBN);
  float bi = bb[c] - m * sc;
  const float* p = Y + (((size_t)b * C + c) * H + h) * Lin + 4u * lo;
  float a0 = p[0] * sc + bi, a1 = p[1] * sc + bi;
  float a2 = p[2] * sc + bi, a3 = p[3] * sc + bi;
  float r = fmaxf(fmaxf(a0, a1), fmaxf(a2, a3));
  Z[idx] = f2bf(fmaxf(r, 0.f));
}

// ---------------------------------------------------------------------------
// BN(train)+ReLU elementwise, fp32 / bf16 out
// ---------------------------------------------------------------------------
__global__ __launch_bounds__(256) void bnrelu_kernel(
    const float* __restrict__ Y, const float* __restrict__ st,
    const float* __restrict__ g, const float* __restrict__ bb,
    float* __restrict__ A, int C, int HL, float invN, unsigned int total) {
  unsigned int idx = blockIdx.x * 256u + threadIdx.x;
  if (idx >= total) return;
  unsigned int c = (idx / (unsigned int)HL) % (unsigned int)C;
  float m = st[c] * invN;
  float v = st[512 + c] * invN - m * m;
  float sc = g[c] * rsqrtf(v + EPSBN);
  float bi = bb[c] - m * sc;
  A[idx] = fmaxf(fmaf(Y[idx], sc, bi), 0.f);
}

__global__ __launch_bounds__(256) void bnrelu_bf16_kernel(
    const float* __restrict__ Y, const float* __restrict__ st,
    const float* __restrict__ g, const float* __restrict__ bb,
    unsigned short* __restrict__ A, int C, int HL, float invN,
    unsigned int total) {
  unsigned int idx = blockIdx.x * 256u + threadIdx.x;
  if (idx >= total) return;
  unsigned int c = (idx / (unsigned int)HL) % (unsigned int)C;
  float m = st[c] * invN;
  float v = st[512 + c] * invN - m * m;
  float sc = g[c] * rsqrtf(v + EPSBN);
  float bi = bb[c] - m * sc;
  A[idx] = f2bf(fmaxf(fmaf(Y[idx], sc, bi), 0.f));
}

// ---------------------------------------------------------------------------
// Pack fp32 weights -> per-s split bf16 packs with 2^-(s+i) folded.
// ---------------------------------------------------------------------------
__global__ __launch_bounds__(256) void pack_w2_kernel(
    const float* __restrict__ W, short* __restrict__ A, int Co, int KTOT,
    int KPAD, int COPAD, int NS, int nk3) {
  int idx = blockIdx.x * 256 + threadIdx.x;
  const int CK = COPAD * KPAD;
  if (idx >= NS * CK) return;
  int s = idx / CK;
  int rem = idx - s * CK;
  int co = rem / KPAD;
  int kk = rem - co * KPAD;
  float v = 0.f;
  if (co < Co && kk < KTOT) {
    int i = (kk % nk3) / 3;
    float scale = __uint_as_float((unsigned)(127 - (s + i)) << 23);
    v = W[co * KTOT + kk] * scale;
  }
  unsigned short hi = f2bf(v);
  unsigned short lo = f2bf(v - bf2f(hi));
  A[(size_t)s * 2 * CK + co * KPAD + kk] = (short)hi;
  A[(size_t)s * 2 * CK + CK + co * KPAD + kk] = (short)lo;
}

// ---------------------------------------------------------------------------
// gg_mfma5: bf16-input MFMA GConvGG, no fused stats (R15, unchanged)
// ---------------------------------------------------------------------------
template <int NKv, int LT>
__global__ __launch_bounds__(256) void gg_mfma5_kernel(
    const unsigned short* __restrict__ X, const short* __restrict__ Apk,
    float* __restrict__ Y, int Ci, int Co, int Hin, int L, int nL, int KTOT,
    int KPAD, int COPAD) {
  constexpr int T = LT / 16;
  constexpr int KO = 256 / LT;
  constexpr int RIT = 8 / KO;

  const int bx = blockIdx.x;
  const int lc = bx % nL;
  const int cog = bx / nL;
  const int s = blockIdx.y;
  const int b = blockIdx.z;
  const int Hout = Hin - NKv + 1;
  const int l0 = lc * LT;
  const int tid = threadIdx.x;
  const int lane = tid & 63;
  const int quad = lane >> 4;
  const int m0 = lane & 15;
  const int wv = tid >> 6;
  const int coBase = cog * 64 + wv * 16;

  __shared__ __align__(16) short Bh[LT * 72];
  __shared__ int roT[512];
  __shared__ int shT[512];

  for (int kk = tid; kk < KPAD; kk += 256) {
    int ro = 0, sh = -(1 << 30);
    if (kk < KTOT) {
      int ci = kk / (3 * NKv);
      int rem = kk - ci * (3 * NKv);
      int i = rem / 3;
      int k = rem - 3 * i;
      ro = (ci * Hin + s + i) * L;
      sh = (k - 1) * (1 << (s + i));
    }
    roT[kk] = ro;
    shT[kk] = sh;
  }
  __syncthreads();

  f32x4 acc[T];
#pragma unroll
  for (int t = 0; t < T; ++t) acc[t] = (f32x4){0.f, 0.f, 0.f, 0.f};

  const short* ApkS = Apk + (size_t)s * 2 * COPAD * KPAD;
  const short* arowH = ApkS + (size_t)(coBase + m0) * KPAD;
  const short* arowL = arowH + (size_t)COPAD * KPAD;
  const unsigned short* Xb = X + (size_t)b * Ci * Hin * L;

  const int lB = tid & (LT - 1);
  const int oc0 = tid / LT;
  const int nch = (KTOT + 63) >> 6;

  uint4 v0[RIT], v1[RIT], v2[RIT];
  auto gather = [&](int c0, uint4 (&pk)[RIT]) {
#pragma unroll
    for (int r = 0; r < RIT; ++r) {
      const int oct = oc0 + KO * r;
      const int kkb = (c0 << 6) + oct * 8;
      unsigned w[8];
#pragma unroll
      for (int j = 0; j < 8; ++j) {
        const int kk = kkb + j;
        const int pos = l0 + lB + shT[kk];
        const int posc = min(max(pos, 0), L - 1);
        unsigned u = (unsigned)Xb[roT[kk] + posc];
        w[j] = ((unsigned)pos < (unsigned)L) ? u : 0u;
      }
      pk[r].x = w[0] | (w[1] << 16);
      pk[r].y = w[2] | (w[3] << 16);
      pk[r].z = w[4] | (w[5] << 16);
      pk[r].w = w[6] | (w[7] << 16);
    }
  };

  gather(0, v0);
  if (nch > 1) gather(1, v1);
  for (int c0 = 0; c0 < nch; ++c0) {
#pragma unroll
    for (int r = 0; r < RIT; ++r)
      *(uint4*)(Bh + lB * 72 + (oc0 + KO * r) * 8) = v0[r];
    if (c0 + 2 < nch) gather(c0 + 2, v2);
    const int a0 = (c0 << 6) + quad * 8;
    short8v ah0 = *(const short8v*)(arowH + a0);
    short8v al0 = *(const short8v*)(arowL + a0);
    short8v ah1 = *(const short8v*)(arowH + a0 + 32);
    short8v al1 = *(const short8v*)(arowL + a0 + 32);
    __syncthreads();
#pragma unroll
    for (int t = 0; t < T; ++t) {
      const int l = m0 + 16 * t;
      short8v b0 = *(const short8v*)(Bh + l * 72 + quad * 8);
      short8v b1 = *(const short8v*)(Bh + l * 72 + 32 + quad * 8);
      acc[t] = __builtin_amdgcn_mfma_f32_16x16x32_bf16(ah0, b0, acc[t], 0, 0, 0);
      acc[t] = __builtin_amdgcn_mfma_f32_16x16x32_bf16(al0, b0, acc[t], 0, 0, 0);
      acc[t] = __builtin_amdgcn_mfma_f32_16x16x32_bf16(ah1, b1, acc[t], 0, 0, 0);
      acc[t] = __builtin_amdgcn_mfma_f32_16x16x32_bf16(al1, b1, acc[t], 0, 0, 0);
    }
    __syncthreads();
#pragma unroll
    for (int r = 0; r < RIT; ++r) {
      v0[r] = v1[r];
      v1[r] = v2[r];
    }
  }

#pragma unroll
  for (int reg = 0; reg < 4; ++reg) {
    const int co = coBase + quad * 4 + reg;
    if (co < Co) {
      float* yp = Y + (((size_t)b * Co + co) * Hout + s) * L + l0;
#pragma unroll
      for (int t = 0; t < T; ++t) yp[m0 + 16 * t] = acc[t][reg];
    }
  }
}

// ---------------------------------------------------------------------------
// gg_tail3: unrolled, atomic-free tail GConvGG.
// UN ci's of loads batched in registers (18-24 loads in flight) before FMAs,
// amortizing the ~900-cyc HBM wait 6-8x vs the serial R15 loop. Plain stores:
// NSPLIT=1 writes Y directly; NSPLIT>1 writes seg-indexed partial buffers
// (reduced by reduce_parts_kernel). No atomics anywhere.
// ---------------------------------------------------------------------------
template <int NK, int L, int COSUB, int UN>
__global__ __launch_bounds__(256) void gg_tail3_kernel(
    const float* __restrict__ X, const float* __restrict__ W,
    float* __restrict__ Y, int Ci, int Co, int Hin, int NSPLIT, int ciPer,
    int partStride) {
  const int l = threadIdx.x % L;
  const int cs = threadIdx.x / L;
  const int co = blockIdx.x * COSUB + cs;
  const int s = blockIdx.y / NSPLIT;
  const int seg = blockIdx.y % NSPLIT;
  const int b = blockIdx.z;
  const int Hout = Hin - NK + 1;
  const int ciBeg = seg * ciPer;
  const int ciEnd = min(Ci, ciBeg + ciPer);

  float acc[NK];
#pragma unroll
  for (int i = 0; i < NK; ++i) acc[i] = 0.f;

  const float* wbase = W + (size_t)co * Ci * NK * 3;
  const float* xbase = X + ((size_t)b * Ci * Hin + s) * L;

  int ci = ciBeg;
  for (; ci + UN <= ciEnd; ci += UN) {
    float xv[UN][NK][3];
#pragma unroll
    for (int u = 0; u < UN; ++u) {
      const float* xr = xbase + (size_t)(ci + u) * (Hin * L);
#pragma unroll
      for (int i = 0; i < NK; ++i) {
        const int d = 1 << (s + i);
        const float* row = xr + i * L;
        xv[u][i][0] = (l >= d) ? row[l - d] : 0.f;
        xv[u][i][1] = row[l];
        xv[u][i][2] = (l + d < L) ? row[l + d] : 0.f;
      }
    }
#pragma unroll
    for (int u = 0; u < UN; ++u) {
      const float* wp = wbase + (ci + u) * (NK * 3);
#pragma unroll
      for (int i = 0; i < NK; ++i)
        acc[i] = fmaf(wp[3 * i], xv[u][i][0],
                      fmaf(wp[3 * i + 1], xv[u][i][1],
                           fmaf(wp[3 * i + 2], xv[u][i][2], acc[i])));
    }
  }
  for (; ci < ciEnd; ++ci) {
    const float* xr = xbase + (size_t)ci * (Hin * L);
    const float* wp = wbase + ci * (NK * 3);
#pragma unroll
    for (int i = 0; i < NK; ++i) {
      const int d = 1 << (s + i);
      const float* row = xr + i * L;
      float xm = (l >= d) ? row[l - d] : 0.f;
      float xc = row[l];
      float xp = (l + d < L) ? row[l + d] : 0.f;
      acc[i] = fmaf(wp[3 * i], xm,
                    fmaf(wp[3 * i + 1], xc, fmaf(wp[3 * i + 2], xp, acc[i])));
    }
  }
  float out = 0.f;
#pragma unroll
  for (int i = 0; i < NK; ++i) {
    float invd = __uint_as_float((unsigned)(127 - (s + i)) << 23);
    out = fmaf(acc[i], invd, out);
  }
  Y[(size_t)seg * partStride + (((size_t)b * Co + co) * Hout + s) * L + l] =
      out;
}

// ---------------------------------------------------------------------------
// Final: bn10+relu, mean over L, classifier
// ---------------------------------------------------------------------------
__global__ __launch_bounds__(256) void final_kernel(
    const float* __restrict__ Y, const float* __restrict__ st,
    const float* __restrict__ g, const float* __restrict__ bb,
    const float* __restrict__ w11, float* __restrict__ out) {
  const int b = blockIdx.x;
  const int tid = threadIdx.x;
  __shared__ float tch[408];
  for (int c = tid; c < 408; c += 256) {
    float m = st[c] * (1.f / 256.f);
    float v = st[512 + c] * (1.f / 256.f) - m * m;
    float sc = g[c] * rsqrtf(v + EPSBN);
    float bi = bb[c] - m * sc;
    const float* p = Y + ((size_t)b * 408 + c) * 32;
    float ssum = 0.f;
#pragma unroll
    for (int l = 0; l < 32; ++l) ssum += fmaxf(p[l] * sc + bi, 0.f);
    tch[c] = ssum * (1.f / 32.f);
  }
  __syncthreads();
  if (tid < 10) {
    float ssum = 0.f;
    for (int c = 0; c < 408; ++c) ssum += w11[tid * 408 + c] * tch[c];
    out[b * 10 + tid] = ssum;
  }
}

// ---------------------------------------------------------------------------
extern "C" void kernel_launch(void* const* d_in, const int* in_sizes, int n_in,
                              void* d_out, int out_size, void* d_ws,
                              size_t ws_size, hipStream_t stream) {
  const float* x = (const float*)d_in[0];
  const float* w1 = (const float*)d_in[1];
  const float* w2 = (const float*)d_in[2];
  const float* w3 = (const float*)d_in[3];
  const float* w4 = (const float*)d_in[4];
  const float* w5 = (const float*)d_in[5];
  const float* w6 = (const float*)d_in[6];
  const float* w7 = (const float*)d_in[7];
  const float* w8 = (const float*)d_in[8];
  const float* w9 = (const float*)d_in[9];
  const float* w10 = (const float*)d_in[10];
  const float* w11 = (const float*)d_in[11];
  const float* gg[11];
  const float* bbv[11];
  for (int i = 1; i <= 10; ++i) {
    gg[i] = (const float*)d_in[12 + 2 * (i - 1)];
    bbv[i] = (const float*)d_in[12 + 2 * (i - 1) + 1];
  }

  float* ws = (float*)d_ws;
  const size_t AR0 = 0;
  const size_t AR1 = 30081024;
  const size_t STATS = 37601280;
  float* y1 = ws + AR0;
  float* xpad = ws + AR1;
  short* apk1 = (short*)(ws + AR1 + 460800);
  unsigned short* z1b = (unsigned short*)(ws + AR1);
  unsigned short* a3b = (unsigned short*)(ws + AR1);
  unsigned short* z3b = (unsigned short*)(ws + AR1);
  unsigned short* a5b = (unsigned short*)(ws + AR1 + 1500000);
  float* z5 = ws + AR1;
  float* a6 = ws + AR1 + 522240;
  float* a7 = ws + AR1 + 1148928;
  float* z8 = ws + AR1;
  float* a9 = ws + AR1 + 1775616;
  float* part9 = ws + AR1 + 1900000;   // 4 * 104448
  float* part10 = ws + AR1 + 2400000;  // 4 * 104448
  float* y2 = ws + AR0;
  float* y3 = ws + AR0 + 5849088;
  float* y4 = ws + AR0;
  float* y5 = ws + AR0 + 2088960;
  float* y6 = ws + AR0;
  float* y7 = ws + AR0 + 626688;
  float* y8 = ws + AR0 + 1253376;
  float* y9 = ws + AR0;
  float* y10 = ws + AR0 + 104448;
  short* apk2 = (short*)(ws + 12000000);
  short* apk3 = apk2 + 7 * 2 * 64 * 512;
  short* apk4 = apk3 + 7 * 2 * 64 * 192;
  short* apk5 = apk4 + 5 * 2 * 128 * 512;
  float* st[11];
  for (int i = 1; i <= 10; ++i) st[i] = ws + STATS + (size_t)(i - 1) * 1024;

  hipMemsetAsync((void*)(ws + STATS), 0, 10 * 1024 * sizeof(float), stream);

  // ---- pad x, pack w1, MFMA lift (+ split stats1 pass)
  pad_x_kernel<<<(8 * PROW + 255) / 256, 256, 0, stream>>>(x, xpad);
  pack_w1_kernel<<<(9 * 64 * 96 + 255) / 256, 256, 0, stream>>>(w1, apk1);
  lift_mfma_kernel<<<dim3(512, 9, 8), 256, 0, stream>>>(xpad, apk1, y1);
  stats_kernel<<<dim3(51, 8, 8), 256, 0, stream>>>(y1, st[1], 51, 9 * 8192, 8);
  {
    unsigned int tot = 8u * 51 * 9 * 2048;
    bnrelu_pool_bf16_kernel<<<(tot + 255) / 256, 256, 0, stream>>>(
        y1, st[1], gg[1], bbv[1], z1b, 51, 9, 8192, 1.f / 589824.f, tot);
  }
  // ---- per-s weight packs
  pack_w2_kernel<<<(7 * 64 * 512 + 255) / 256, 256, 0, stream>>>(
      w2, apk2, 51, 459, 512, 64, 7, 9);
  pack_w2_kernel<<<(7 * 64 * 192 + 255) / 256, 256, 0, stream>>>(
      w3, apk3, 51, 153, 192, 64, 7, 3);
  pack_w2_kernel<<<(5 * 128 * 512 + 255) / 256, 256, 0, stream>>>(
      w4, apk4, 102, 459, 512, 128, 5, 9);
  pack_w2_kernel<<<(5 * 128 * 320 + 255) / 256, 256, 0, stream>>>(
      w5, apk5, 102, 306, 320, 128, 5, 3);
  // ---- gg2: 51->51, H 9->7, L=2048
  gg_mfma5_kernel<3, 64><<<dim3(32, 7, 8), 256, 0, stream>>>(
      z1b, apk2, y2, 51, 51, 9, 2048, 32, 459, 512, 64);
  stats_kernel<<<dim3(51, 8, 4), 256, 0, stream>>>(y2, st[2], 51, 7 * 2048, 4);
  {
    unsigned int tot = 8u * 51 * 7 * 2048;
    bnrelu_bf16_kernel<<<(tot + 255) / 256, 256, 0, stream>>>(
        y2, st[2], gg[2], bbv[2], a3b, 51, 7 * 2048, 1.f / 114688.f, tot);
  }
  // ---- gg3: 51->51, H7, L=2048
  gg_mfma5_kernel<1, 64><<<dim3(32, 7, 8), 256, 0, stream>>>(
      a3b, apk3, y3, 51, 51, 7, 2048, 32, 153, 192, 64);
  stats_kernel<<<dim3(51, 8, 4), 256, 0, stream>>>(y3, st[3], 51, 7 * 2048, 4);
  {
    unsigned int tot = 8u * 51 * 7 * 512;
    bnrelu_pool_bf16_kernel<<<(tot + 255) / 256, 256, 0, stream>>>(
        y3, st[3], gg[3], bbv[3], z3b, 51, 7, 2048, 1.f / 114688.f, tot);
  }
  // ---- gg4: 51->102, H 7->5, L=512
  gg_mfma5_kernel<3, 32><<<dim3(32, 5, 8), 256, 0, stream>>>(
      z3b, apk4, y4, 51, 102, 7, 512, 16, 459, 512, 128);
  stats_kernel<<<dim3(102, 8, 2), 256, 0, stream>>>(y4, st[4], 102, 5 * 512,
                                                    2);
  {
    unsigned int tot = 8u * 102 * 5 * 512;
    bnrelu_bf16_kernel<<<(tot + 255) / 256, 256, 0, stream>>>(
        y4, st[4], gg[4], bbv[4], a5b, 102, 5 * 512, 1.f / 20480.f, tot);
  }
  // ---- gg5: 102->102, H5, L=512
  gg_mfma5_kernel<1, 32><<<dim3(32, 5, 8), 256, 0, stream>>>(
      a5b, apk5, y5, 102, 102, 5, 512, 16, 306, 320, 128);
  stats_kernel<<<dim3(102, 8, 2), 256, 0, stream>>>(y5, st[5], 102, 5 * 512,
                                                    2);
  {
    unsigned int tot = 8u * 102 * 5 * 128;
    bnrelu_pool_kernel<<<(tot + 255) / 256, 256, 0, stream>>>(
        y5, st[5], gg[5], bbv[5], z5, 102, 5, 512, 1.f / 20480.f, tot);
  }
  // ---- gg6: 102->204, H 5->3, L=128 (unrolled, direct store)
  gg_tail3_kernel<3, 128, 2, 2><<<dim3(102, 3, 8), 256, 0, stream>>>(
      z5, w6, y6, 102, 204, 5, 1, 102, 0);
  stats_kernel<<<dim3(204, 8, 1), 256, 0, stream>>>(y6, st[6], 204, 384, 1);
  {
    unsigned int tot = 8u * 204 * 3 * 128;
    bnrelu_kernel<<<(tot + 255) / 256, 256, 0, stream>>>(
        y6, st[6], gg[6], bbv[6], a6, 204, 3 * 128, 1.f / 3072.f, tot);
  }
  // ---- gg7: 204->204, H3, L=128
  gg_tail3_kernel<1, 128, 2, 8><<<dim3(102, 3, 8), 256, 0, stream>>>(
      a6, w7, y7, 204, 204, 3, 1, 204, 0);
  stats_kernel<<<dim3(204, 8, 1), 256, 0, stream>>>(y7, st[7], 204, 384, 1);
  {
    unsigned int tot = 8u * 204 * 3 * 128;
    bnrelu_kernel<<<(tot + 255) / 256, 256, 0, stream>>>(
        y7, st[7], gg[7], bbv[7], a7, 204, 3 * 128, 1.f / 3072.f, tot);
  }
  // ---- gg8: 204->204, H3, L=128
  gg_tail3_kernel<1, 128, 2, 8><<<dim3(102, 3, 8), 256, 0, stream>>>(
      a7, w8, y8, 204, 204, 3, 1, 204, 0);
  stats_kernel<<<dim3(204, 8, 1), 256, 0, stream>>>(y8, st[8], 204, 384, 1);
  {
    unsigned int tot = 8u * 204 * 3 * 32;
    bnrelu_pool_kernel<<<(tot + 255) / 256, 256, 0, stream>>>(
        y8, st[8], gg[8], bbv[8], z8, 204, 3, 128, 1.f / 3072.f, tot);
  }
  // ---- gg9: 204->408, H 3->1, L=32 (K-split x4 into partials, reduce)
  gg_tail3_kernel<3, 32, 8, 2><<<dim3(51, 4, 8), 256, 0, stream>>>(
      z8, w9, part9, 204, 408, 3, 4, 51, 104448);
  reduce_parts_kernel<<<(104448 + 255) / 256, 256, 0, stream>>>(
      part9, y9, 104448, 104448, 4);
  stats_kernel<<<dim3(408, 8, 1), 256, 0, stream>>>(y9, st[9], 408, 32, 1);
  {
    unsigned int tot = 8u * 408 * 32;
    bnrelu_kernel<<<(tot + 255) / 256, 256, 0, stream>>>(
        y9, st[9], gg[9], bbv[9], a9, 408, 32, 1.f / 256.f, tot);
  }
  // ---- gg10: 408->408, H1, L=32 (K-split x4 into partials, reduce)
  gg_tail3_kernel<1, 32, 8, 8><<<dim3(51, 4, 8), 256, 0, stream>>>(
      a9, w10, part10, 408, 408, 1, 4, 102, 104448);
  reduce_parts_kernel<<<(104448 + 255) / 256, 256, 0, stream>>>(
      part10, y10, 104448, 104448, 4);
  stats_kernel<<<dim3(408, 8, 1), 256, 0, stream>>>(y10, st[10], 408, 32, 1);
  // ---- final
  final_kernel<<<dim3(8), 256, 0, stream>>>(y10, st[10], gg[10], bbv[10], w11,
                                            (float*)d_out);
}